// Round 2
// baseline (230.210 us; speedup 1.0000x reference)
//
#include <hip/hip_runtime.h>
#include <math.h>

#define BB 16
#define TT 2048
#define DD 256
#define KK 8
#define CC 16          // T-chunks for partial accumulation
static constexpr float LN_EPS = 1e-5f;

// ---------------------------------------------------------------------------
// Kernel A: one THREAD per token. Per-lane sequential dot over D (L1-friendly),
// center loads are wave-uniform -> scalar. No cross-lane ops. Writes w (B*T,K).
// ---------------------------------------------------------------------------
__global__ __launch_bounds__(128) void lde_weights(
    const float* __restrict__ x,
    const float* __restrict__ centers,
    const float* __restrict__ scale,
    const float* __restrict__ temperature,
    float* __restrict__ w)
{
    const int tid = threadIdx.x;
    const int t   = blockIdx.x * 128 + tid;        // global token 0..32767
    const float4* cv = reinterpret_cast<const float4*>(centers);

    // block-shared center norms (computed once by 32 threads)
    __shared__ float lds_c2[KK];
    if (tid < KK) lds_c2[tid] = 0.0f;
    __syncthreads();
    if (tid < 32) {
        const int k = tid >> 2, q = tid & 3;
        const float4* cq = cv + k * 64 + q * 16;
        float p = 0.0f;
        #pragma unroll
        for (int i = 0; i < 16; ++i) {
            float4 c = cq[i];
            p = fmaf(c.x, c.x, fmaf(c.y, c.y, fmaf(c.z, c.z, fmaf(c.w, c.w, p))));
        }
        atomicAdd(&lds_c2[k], p);
    }
    __syncthreads();

    const float4* xr = reinterpret_cast<const float4*>(x) + (size_t)t * 64;
    float dot[KK] = {};
    float x2 = 0.0f;
    #pragma unroll 4
    for (int i = 0; i < 64; ++i) {
        const float4 xv = xr[i];
        x2 = fmaf(xv.x, xv.x, fmaf(xv.y, xv.y, fmaf(xv.z, xv.z, fmaf(xv.w, xv.w, x2))));
        #pragma unroll
        for (int k = 0; k < KK; ++k) {
            const float4 c = cv[k * 64 + i];   // uniform address -> s_load
            dot[k] = fmaf(xv.x, c.x, fmaf(xv.y, c.y, fmaf(xv.z, c.z, fmaf(xv.w, c.w, dot[k]))));
        }
    }

    const float temp = temperature[0];
    float lg[KK];
    float m = -3.4e38f;
    #pragma unroll
    for (int k = 0; k < KK; ++k) {
        const float dist = x2 - 2.0f * dot[k] + lds_c2[k];
        lg[k] = -temp * scale[k] * dist;
        m = fmaxf(m, lg[k]);
    }
    float s = 0.0f;
    float p[KK];
    #pragma unroll
    for (int k = 0; k < KK; ++k) { p[k] = __expf(lg[k] - m); s += p[k]; }
    const float inv = 1.0f / s;

    float4* wv = reinterpret_cast<float4*>(w) + (size_t)t * 2;
    wv[0] = make_float4(p[0] * inv, p[1] * inv, p[2] * inv, p[3] * inv);
    wv[1] = make_float4(p[4] * inv, p[5] * inv, p[6] * inv, p[7] * inv);
}

// ---------------------------------------------------------------------------
// Kernel B: accumulate s_w, s_wx, s_wx2 per (b, chunk). 1024 thr = 16 waves,
// wave owns 8 tokens, lane owns d=4l..4l+3. Weights are wave-uniform scalar
// loads; the token loop is pure independent FMAs (no shuffles, no softmax).
// ---------------------------------------------------------------------------
__global__ __launch_bounds__(1024) void lde_accum2(
    const float* __restrict__ x,
    const float* __restrict__ w,
    float* __restrict__ ws_wx,   // [B*CC][K][512] (0..255 wx | 256..511 wx2)
    float* __restrict__ ws_w)    // [B*CC][K]
{
    const int c    = blockIdx.x;      // 0..CC-1
    const int b    = blockIdx.y;
    const int tid  = threadIdx.x;
    const int wave = tid >> 6;        // 0..15
    const int lane = tid & 63;

    const int TC  = TT / CC;          // 128 tokens per block
    const int TPW = TC / 16;          // 8 tokens per wave
    const int t0  = c * TC + wave * TPW;   // batch-local token

    __shared__ float lds_acc[KK * 512];
    __shared__ float lds_w[KK];
    for (int i = tid; i < KK * 512; i += 1024) lds_acc[i] = 0.0f;
    if (tid < KK) lds_w[tid] = 0.0f;

    const float4* xrow = reinterpret_cast<const float4*>(x + (size_t)b * TT * DD);
    const float*  wrow = w + (size_t)b * TT * KK;

    float accw[KK]      = {};
    float accwx[KK][4]  = {};
    float accwx2[KK][4] = {};

    float4 xv = xrow[(size_t)t0 * 64 + lane];
    for (int i = 0; i < TPW; ++i) {
        const float4 cur = xv;
        if (i + 1 < TPW) xv = xrow[(size_t)(t0 + i + 1) * 64 + lane];

        const float* wp = wrow + (size_t)(t0 + i) * KK;  // uniform -> s_load
        float wk[KK];
        #pragma unroll
        for (int k = 0; k < KK; ++k) wk[k] = wp[k];

        const float xx0 = cur.x * cur.x, xx1 = cur.y * cur.y;
        const float xx2 = cur.z * cur.z, xx3 = cur.w * cur.w;
        #pragma unroll
        for (int k = 0; k < KK; ++k) {
            accw[k] += wk[k];
            accwx[k][0]  = fmaf(wk[k], cur.x, accwx[k][0]);
            accwx[k][1]  = fmaf(wk[k], cur.y, accwx[k][1]);
            accwx[k][2]  = fmaf(wk[k], cur.z, accwx[k][2]);
            accwx[k][3]  = fmaf(wk[k], cur.w, accwx[k][3]);
            accwx2[k][0] = fmaf(wk[k], xx0, accwx2[k][0]);
            accwx2[k][1] = fmaf(wk[k], xx1, accwx2[k][1]);
            accwx2[k][2] = fmaf(wk[k], xx2, accwx2[k][2]);
            accwx2[k][3] = fmaf(wk[k], xx3, accwx2[k][3]);
        }
    }

    __syncthreads();   // LDS zeroed + all waves done

    #pragma unroll
    for (int kk = 0; kk < KK; ++kk) {
        const int k = (kk + wave) & (KK - 1);
        float* wxp  = &lds_acc[k * 512 + 4 * lane];
        float* wx2p = &lds_acc[k * 512 + 256 + 4 * lane];
        atomicAdd(&wxp[0],  accwx[k][0]);  atomicAdd(&wxp[1],  accwx[k][1]);
        atomicAdd(&wxp[2],  accwx[k][2]);  atomicAdd(&wxp[3],  accwx[k][3]);
        atomicAdd(&wx2p[0], accwx2[k][0]); atomicAdd(&wx2p[1], accwx2[k][1]);
        atomicAdd(&wx2p[2], accwx2[k][2]); atomicAdd(&wx2p[3], accwx2[k][3]);
        if (lane == 0) atomicAdd(&lds_w[k], accw[k]);
    }
    __syncthreads();

    float* dst = ws_wx + ((size_t)(b * CC + c) * KK) * 512;
    for (int i = tid; i < KK * 512; i += 1024) dst[i] = lds_acc[i];
    if (tid < KK) ws_w[(size_t)(b * CC + c) * KK + tid] = lds_w[tid];
}

// ---------------------------------------------------------------------------
// Kernel C: per (b,k): coalesced reduction over CC chunks, mean/var, layernorm.
// ---------------------------------------------------------------------------
__global__ __launch_bounds__(256) void lde_final2(
    const float* __restrict__ ws_wx,
    const float* __restrict__ ws_w,
    const float* __restrict__ centers,
    float* __restrict__ out)
{
    const int b = blockIdx.x >> 3;
    const int k = blockIdx.x & 7;
    const int tid  = threadIdx.x;
    const int half = tid >> 7;        // 0..1
    const int j    = tid & 127;       // float4 index within 512-chunk

    const float4* base = reinterpret_cast<const float4*>(ws_wx);
    float ax = 0.f, ay = 0.f, az = 0.f, aw = 0.f;
    #pragma unroll
    for (int ci = half; ci < CC; ci += 2) {
        const float4 v = base[((size_t)((b * CC + ci) * KK + k)) * 128 + j];
        ax += v.x; ay += v.y; az += v.z; aw += v.w;
    }

    __shared__ float4 l4[256];
    __shared__ float  sum[512];
    l4[tid] = make_float4(ax, ay, az, aw);
    __syncthreads();
    if (tid < 128) {
        const float4 u = l4[tid], v = l4[tid + 128];
        reinterpret_cast<float4*>(sum)[tid] =
            make_float4(u.x + v.x, u.y + v.y, u.z + v.z, u.w + v.w);
    }

    float sw = 0.0f;
    #pragma unroll
    for (int ci = 0; ci < CC; ++ci) sw += ws_w[(size_t)(b * CC + ci) * KK + k];
    __syncthreads();

    const int d = tid;
    const float wx  = sum[d];
    const float wx2 = sum[256 + d];
    const float ck  = centers[k * DD + d];
    const float mean = wx - ck * sw;
    const float E    = wx2 - 2.0f * ck * wx + ck * ck * sw;
    const float var  = E - mean * mean;

    // layernorm over 512 (each thread holds mean_d and var_d)
    float s1 = mean + var;
    float s2 = mean * mean + var * var;
    #pragma unroll
    for (int off = 32; off >= 1; off >>= 1) {
        s1 += __shfl_xor(s1, off, 64);
        s2 += __shfl_xor(s2, off, 64);
    }
    __shared__ float l1[4], l2[4];
    const int wave = tid >> 6, lane = tid & 63;
    if (lane == 0) { l1[wave] = s1; l2[wave] = s2; }
    __syncthreads();
    const float S1 = l1[0] + l1[1] + l1[2] + l1[3];
    const float S2 = l2[0] + l2[1] + l2[2] + l2[3];

    const float mu   = S1 * (1.0f / 512.0f);
    const float v    = S2 * (1.0f / 512.0f) - mu * mu;
    const float rinv = rsqrtf(v + LN_EPS);

    const size_t o = (size_t)b * (KK * 512) + (size_t)k * 512;
    out[o + d]       = (mean - mu) * rinv;
    out[o + 256 + d] = (var  - mu) * rinv;
}

// ---------------------------------------------------------------------------
extern "C" void kernel_launch(void* const* d_in, const int* in_sizes, int n_in,
                              void* d_out, int out_size, void* d_ws, size_t ws_size,
                              hipStream_t stream)
{
    const float* x       = (const float*)d_in[0];
    const float* centers = (const float*)d_in[1];
    const float* scale   = (const float*)d_in[2];
    const float* temp    = (const float*)d_in[3];
    float* out = (float*)d_out;

    float* w     = (float*)d_ws;                         // B*T*K   = 1 MB
    float* ws_wx = w + (size_t)BB * TT * KK;             // B*CC*K*512 = 4.2 MB
    float* ws_w  = ws_wx + (size_t)BB * CC * KK * 512;   // B*CC*K  = 8 KB

    lde_weights<<<(BB * TT) / 128, 128, 0, stream>>>(x, centers, scale, temp, w);

    dim3 g2(CC, BB);
    lde_accum2<<<g2, 1024, 0, stream>>>(x, w, ws_wx, ws_w);

    lde_final2<<<BB * KK, 256, 0, stream>>>(ws_wx, ws_w, centers, out);
}

// Round 3
// 183.900 us; speedup vs baseline: 1.2518x; 1.2518x over previous
//
#include <hip/hip_runtime.h>
#include <math.h>

#define BB 16
#define TT 2048
#define DD 256
#define KK 8
static constexpr float LN_EPS = 1e-5f;

// DPP lane exchange (VALU, no LDS pipe, no waitcnt). CTRL: 0xB1 = quad_perm
// xor1, 0x4E = quad_perm xor2, 0x108 = row_shl:8, 0x118 = row_shr:8.
template<int CTRL>
__device__ __forceinline__ float dppf(float x) {
    return __int_as_float(__builtin_amdgcn_update_dpp(
        0, __float_as_int(x), CTRL, 0xF, 0xF, true));
}

// ---------------------------------------------------------------------------
// Fused kernel: one pass over x. Wave owns TPW tokens; lane owns d=4l..4l+3.
// Per token: per-lane partials of q[k] = temp*scale[k]*dist_k, halving
// reduction over lane bits {0,1,4} (DPP + 1 shfl), broadcast-reduce bits
// {2,3,5}, DPP allgather -> every lane holds all 8 totals as E[m] where the
// cluster id is k = v(lane) ^ m.  Softmax is order-free; accumulators are
// kept in m-order and unpermuted once in the epilogue.
// ---------------------------------------------------------------------------
__global__ __launch_bounds__(256) void lde_fused(
    const float* __restrict__ x,
    const float* __restrict__ centers,
    const float* __restrict__ scale,
    const float* __restrict__ temperature,
    float* __restrict__ ws_wx,   // [BB*C][KK*512] (0..255 wx | 256..511 wx2)
    float* __restrict__ ws_w,    // [BB*C][KK]
    int C, int TPW)
{
    const int c    = blockIdx.x;
    const int b    = blockIdx.y;
    const int tid  = threadIdx.x;
    const int wave = tid >> 6;       // 0..3
    const int lane = tid & 63;

    __shared__ float lds_acc[KK * 512];
    __shared__ float lds_w[KK];
    #pragma unroll
    for (int i = 0; i < (KK * 512) / 256; ++i) lds_acc[i * 256 + tid] = 0.0f;
    if (tid < KK) lds_w[tid] = 0.0f;

    // Per-lane center fragments; fold -2*temp*scale into the fragment so the
    // per-token dot directly yields -2*ts*x.c ; Bc = ts*c2 (per-lane partial).
    const float4* cv = reinterpret_cast<const float4*>(centers);
    const float temp = temperature[0];
    float4 c4s[KK]; float A[KK], Bc[KK];
    #pragma unroll
    for (int k = 0; k < KK; ++k) {
        const float4 cc = cv[k * 64 + lane];
        const float a = temp * scale[k];
        A[k]  = a;
        Bc[k] = a * (cc.x*cc.x + cc.y*cc.y + cc.z*cc.z + cc.w*cc.w);
        const float na = -2.0f * a;
        c4s[k] = make_float4(na*cc.x, na*cc.y, na*cc.z, na*cc.w);
    }

    const int bit0 = lane & 1;
    const int bit1 = (lane >> 1) & 1;
    const int bit4 = (lane >> 4) & 1;
    const int v    = (bit0 << 2) | (bit1 << 1) | bit4;   // value held after reduce

    float accw[KK]      = {};
    float accx[KK][4]   = {};
    float accx2[KK][4]  = {};

    const int t0 = (c * 4 + wave) * TPW;
    const float4* xr = reinterpret_cast<const float4*>(x + (size_t)b * TT * DD);

    float4 xv = xr[(size_t)t0 * 64 + lane];
    for (int i = 0; i < TPW; ++i) {
        const float4 cx = xv;
        if (i + 1 < TPW) xv = xr[(size_t)(t0 + i + 1) * 64 + lane];

        const float x2p = fmaf(cx.x,cx.x, fmaf(cx.y,cx.y, fmaf(cx.z,cx.z, cx.w*cx.w)));
        float q[KK];
        #pragma unroll
        for (int k = 0; k < KK; ++k) {
            const float rp = fmaf(cx.x,c4s[k].x, fmaf(cx.y,c4s[k].y,
                             fmaf(cx.z,c4s[k].z, cx.w*c4s[k].w)));
            q[k] = rp + fmaf(A[k], x2p, Bc[k]);    // ts*(x2 - 2x.c + c2) partial
        }

        // ---- halving reduce: lane bit0 (qp xor1), bit1 (qp xor2), bit4 (shfl16)
        float a0, a1, a2, a3;
        {
            const float s_0 = bit0 ? q[0] : q[4];
            const float s_1 = bit0 ? q[1] : q[5];
            const float s_2 = bit0 ? q[2] : q[6];
            const float s_3 = bit0 ? q[3] : q[7];
            const float k_0 = bit0 ? q[4] : q[0];
            const float k_1 = bit0 ? q[5] : q[1];
            const float k_2 = bit0 ? q[6] : q[2];
            const float k_3 = bit0 ? q[7] : q[3];
            a0 = k_0 + dppf<0xB1>(s_0);
            a1 = k_1 + dppf<0xB1>(s_1);
            a2 = k_2 + dppf<0xB1>(s_2);
            a3 = k_3 + dppf<0xB1>(s_3);
        }
        float b0, b1;
        {
            const float s_0 = bit1 ? a0 : a2;
            const float s_1 = bit1 ? a1 : a3;
            const float k_0 = bit1 ? a2 : a0;
            const float k_1 = bit1 ? a3 : a1;
            b0 = k_0 + dppf<0x4E>(s_0);
            b1 = k_1 + dppf<0x4E>(s_1);
        }
        float S;
        {
            const float s_ = bit4 ? b0 : b1;
            const float k_ = bit4 ? b1 : b0;
            S = k_ + __shfl_xor(s_, 16, 64);
        }
        // ---- broadcast-reduce remaining lane bits 2, 3, 5
        S += __shfl_xor(S, 4, 64);
        S += dppf<0x108>(S) + dppf<0x118>(S);   // bit3: shl8 + shr8 (0-filled)
        S += __shfl_xor(S, 32, 64);

        // ---- allgather: E[m] = total q for cluster (v ^ m)
        const float E0 = S;
        const float E1 = __shfl_xor(S, 16, 64);
        const float E2 = dppf<0x4E>(E0);
        const float E3 = dppf<0x4E>(E1);
        const float E4 = dppf<0xB1>(E0);
        const float E5 = dppf<0xB1>(E1);
        const float E6 = dppf<0xB1>(E2);
        const float E7 = dppf<0xB1>(E3);

        // ---- softmax over 8 values (order-free). logit = -q.
        const float mn = fminf(fminf(fminf(E0,E1),fminf(E2,E3)),
                               fminf(fminf(E4,E5),fminf(E6,E7)));
        float W[KK];
        W[0]=__expf(mn-E0); W[1]=__expf(mn-E1); W[2]=__expf(mn-E2); W[3]=__expf(mn-E3);
        W[4]=__expf(mn-E4); W[5]=__expf(mn-E5); W[6]=__expf(mn-E6); W[7]=__expf(mn-E7);
        const float ssum = ((W[0]+W[1])+(W[2]+W[3])) + ((W[4]+W[5])+(W[6]+W[7]));
        const float inv  = 1.0f / ssum;

        const float xx0 = cx.x*cx.x, xx1 = cx.y*cx.y;
        const float xx2 = cx.z*cx.z, xx3 = cx.w*cx.w;
        #pragma unroll
        for (int m = 0; m < KK; ++m) {
            const float w = W[m] * inv;
            accw[m] += w;
            accx[m][0]  = fmaf(w, cx.x, accx[m][0]);
            accx[m][1]  = fmaf(w, cx.y, accx[m][1]);
            accx[m][2]  = fmaf(w, cx.z, accx[m][2]);
            accx[m][3]  = fmaf(w, cx.w, accx[m][3]);
            accx2[m][0] = fmaf(w, xx0, accx2[m][0]);
            accx2[m][1] = fmaf(w, xx1, accx2[m][1]);
            accx2[m][2] = fmaf(w, xx2, accx2[m][2]);
            accx2[m][3] = fmaf(w, xx3, accx2[m][3]);
        }
    }

    __syncthreads();   // zeroing + all waves finished

    // Epilogue (once per kernel): unpermute k = v ^ m and combine in LDS.
    #pragma unroll
    for (int m = 0; m < KK; ++m) {
        const int k = v ^ m;
        float* p = &lds_acc[k * 512 + 4 * lane];
        atomicAdd(p + 0,   accx[m][0]);  atomicAdd(p + 1,   accx[m][1]);
        atomicAdd(p + 2,   accx[m][2]);  atomicAdd(p + 3,   accx[m][3]);
        atomicAdd(p + 256, accx2[m][0]); atomicAdd(p + 257, accx2[m][1]);
        atomicAdd(p + 258, accx2[m][2]); atomicAdd(p + 259, accx2[m][3]);
    }
    if (lane == 0) {   // accw is wave-uniform per cluster: one lane contributes
        #pragma unroll
        for (int m = 0; m < KK; ++m) atomicAdd(&lds_w[m], accw[m]);  // lane0: v=0
    }
    __syncthreads();

    float* dst = ws_wx + (size_t)(b * C + c) * (KK * 512);
    #pragma unroll
    for (int i = 0; i < (KK * 512) / 256; ++i) dst[i * 256 + tid] = lds_acc[i * 256 + tid];
    if (tid < KK) ws_w[(size_t)(b * C + c) * KK + tid] = lds_w[tid];
}

// ---------------------------------------------------------------------------
// Final: per (b,k) reduce over C chunks, mean/var (reference decomposition),
// layernorm over 512, write out.
// ---------------------------------------------------------------------------
__global__ __launch_bounds__(256) void lde_final3(
    const float* __restrict__ ws_wx,
    const float* __restrict__ ws_w,
    const float* __restrict__ centers,
    float* __restrict__ out,
    int C)
{
    const int b = blockIdx.x >> 3;
    const int k = blockIdx.x & 7;
    const int tid  = threadIdx.x;
    const int half = tid >> 7;        // 0..1
    const int j    = tid & 127;       // float4 index within the 512-chunk

    const float4* base = reinterpret_cast<const float4*>(ws_wx);
    float ax = 0.f, ay = 0.f, az = 0.f, aw = 0.f;
    #pragma unroll 4
    for (int ci = half; ci < C; ci += 2) {
        const float4 vv = base[((size_t)((b * C + ci) * KK + k)) * 128 + j];
        ax += vv.x; ay += vv.y; az += vv.z; aw += vv.w;
    }

    __shared__ float4 l4[256];
    __shared__ float  sum[512];
    l4[tid] = make_float4(ax, ay, az, aw);
    __syncthreads();
    if (tid < 128) {
        const float4 u = l4[tid], vv = l4[tid + 128];
        reinterpret_cast<float4*>(sum)[tid] =
            make_float4(u.x + vv.x, u.y + vv.y, u.z + vv.z, u.w + vv.w);
    }

    float sw = 0.0f;
    for (int ci = 0; ci < C; ++ci) sw += ws_w[(size_t)(b * C + ci) * KK + k];
    __syncthreads();

    const int d = tid;
    const float wx   = sum[d];
    const float wx2  = sum[256 + d];
    const float ck   = centers[k * DD + d];
    const float mean = wx - ck * sw;
    const float E    = wx2 - 2.0f * ck * wx + ck * ck * sw;
    const float var  = E - mean * mean;

    float s1 = mean + var;
    float s2 = mean * mean + var * var;
    #pragma unroll
    for (int off = 32; off >= 1; off >>= 1) {
        s1 += __shfl_xor(s1, off, 64);
        s2 += __shfl_xor(s2, off, 64);
    }
    __shared__ float l1[4], l2[4];
    const int wv = tid >> 6, lane = tid & 63;
    if (lane == 0) { l1[wv] = s1; l2[wv] = s2; }
    __syncthreads();
    const float S1 = l1[0] + l1[1] + l1[2] + l1[3];
    const float S2 = l2[0] + l2[1] + l2[2] + l2[3];

    const float mu   = S1 * (1.0f / 512.0f);
    const float vr   = S2 * (1.0f / 512.0f) - mu * mu;
    const float rinv = rsqrtf(vr + LN_EPS);

    const size_t o = (size_t)b * (KK * 512) + (size_t)k * 512;
    out[o + d]       = (mean - mu) * rinv;
    out[o + 256 + d] = (var  - mu) * rinv;
}

// ---------------------------------------------------------------------------
extern "C" void kernel_launch(void* const* d_in, const int* in_sizes, int n_in,
                              void* d_out, int out_size, void* d_ws, size_t ws_size,
                              hipStream_t stream)
{
    const float* x       = (const float*)d_in[0];
    const float* centers = (const float*)d_in[1];
    const float* scale   = (const float*)d_in[2];
    const float* temp    = (const float*)d_in[3];
    float* out = (float*)d_out;

    int C = 64;
    while (C > 2 && ((size_t)BB * C * KK * 512 + (size_t)BB * C * KK) * 4 > ws_size)
        C >>= 1;
    const int TPW = TT / (C * 4);   // tokens per wave (4 waves/block)

    float* ws_wx = (float*)d_ws;
    float* ws_w  = ws_wx + (size_t)BB * C * KK * 512;

    dim3 g1(C, BB);
    lde_fused<<<g1, 256, 0, stream>>>(x, centers, scale, temp, ws_wx, ws_w, C, TPW);
    lde_final3<<<BB * KK, 256, 0, stream>>>(ws_wx, ws_w, centers, out, C);
}

// Round 4
// 178.324 us; speedup vs baseline: 1.2910x; 1.0313x over previous
//
#include <hip/hip_runtime.h>
#include <math.h>

#define BB 16
#define TT 2048
#define DD 256
#define KK 8
static constexpr float LN_EPS = 1e-5f;

// DPP lane exchange (VALU, no LDS pipe). 0xB1=quad_perm xor1, 0x4E=quad_perm
// xor2, 0x108=row_shl:8, 0x118=row_shr:8 (row=16 lanes, zero-fill).
template<int CTRL>
__device__ __forceinline__ float dppf(float x) {
    return __int_as_float(__builtin_amdgcn_update_dpp(
        0, __float_as_int(x), CTRL, 0xF, 0xF, true));
}

// ---------------------------------------------------------------------------
// Fused single-pass kernel. Wave owns TPW tokens; lane owns d=4l..4l+3.
// __launch_bounds__(256,3): VGPR cap ~170 so the 72 accumulator regs + 48
// center-frag regs stay in registers (rounds 1-3 were scratch-spill-bound at
// VGPR=80). 3 waves/SIMD overlap the per-token DS-reduce chains.
// ---------------------------------------------------------------------------
__global__ __launch_bounds__(256, 3) void lde_fused(
    const float* __restrict__ x,
    const float* __restrict__ centers,
    const float* __restrict__ scale,
    const float* __restrict__ temperature,
    float* __restrict__ ws_wx,   // [BB*C][KK*512] (0..255 wx | 256..511 wx2)
    float* __restrict__ ws_w,    // [BB*C][KK]
    int C, int TPW)
{
    const int c    = blockIdx.x;
    const int b    = blockIdx.y;
    const int tid  = threadIdx.x;
    const int wave = tid >> 6;
    const int lane = tid & 63;

    __shared__ float lds_acc[KK * 512];
    __shared__ float lds_w[KK];
    #pragma unroll
    for (int i = 0; i < (KK * 512) / 256; ++i) lds_acc[i * 256 + tid] = 0.0f;
    if (tid < KK) lds_w[tid] = 0.0f;

    // fold -2*temp*scale into center fragments; Bc = ts * |c-quad|^2 partial
    const float4* cv = reinterpret_cast<const float4*>(centers);
    const float temp = temperature[0];
    float4 c4s[KK]; float A[KK], Bc[KK];
    #pragma unroll
    for (int k = 0; k < KK; ++k) {
        const float4 cc = cv[k * 64 + lane];
        const float a = temp * scale[k];
        A[k]  = a;
        Bc[k] = a * (cc.x*cc.x + cc.y*cc.y + cc.z*cc.z + cc.w*cc.w);
        const float na = -2.0f * a;
        c4s[k] = make_float4(na*cc.x, na*cc.y, na*cc.z, na*cc.w);
    }

    const int bit0 = lane & 1;
    const int bit1 = (lane >> 1) & 1;
    const int bit4 = (lane >> 4) & 1;
    const int v    = (bit0 << 2) | (bit1 << 1) | bit4;

    float accw[KK]     = {};
    float accx[KK][4]  = {};
    float accx2[KK][4] = {};

    const int t0 = (c * 4 + wave) * TPW;
    const float4* xr = reinterpret_cast<const float4*>(x + (size_t)b * TT * DD);

    // 2-deep prefetch: 2 outstanding global loads per wave
    float4 cur = xr[(size_t)t0 * 64 + lane];
    float4 nx1 = xr[(size_t)(t0 + 1) * 64 + lane];
    for (int i = 0; i < TPW; ++i) {
        const float4 cx = cur;
        float4 nx2;
        if (i + 2 < TPW) nx2 = xr[(size_t)(t0 + i + 2) * 64 + lane];
        cur = nx1; nx1 = nx2;

        const float x2p = fmaf(cx.x,cx.x, fmaf(cx.y,cx.y, fmaf(cx.z,cx.z, cx.w*cx.w)));
        float q[KK];
        #pragma unroll
        for (int k = 0; k < KK; ++k) {
            const float rp = fmaf(cx.x,c4s[k].x, fmaf(cx.y,c4s[k].y,
                             fmaf(cx.z,c4s[k].z, cx.w*c4s[k].w)));
            q[k] = rp + fmaf(A[k], x2p, Bc[k]);
        }

        // halving reduce over lane bits 0 (qp xor1), 1 (qp xor2), 4 (shfl16)
        float a0, a1, a2, a3;
        {
            const float s_0 = bit0 ? q[0] : q[4];
            const float s_1 = bit0 ? q[1] : q[5];
            const float s_2 = bit0 ? q[2] : q[6];
            const float s_3 = bit0 ? q[3] : q[7];
            const float k_0 = bit0 ? q[4] : q[0];
            const float k_1 = bit0 ? q[5] : q[1];
            const float k_2 = bit0 ? q[6] : q[2];
            const float k_3 = bit0 ? q[7] : q[3];
            a0 = k_0 + dppf<0xB1>(s_0);
            a1 = k_1 + dppf<0xB1>(s_1);
            a2 = k_2 + dppf<0xB1>(s_2);
            a3 = k_3 + dppf<0xB1>(s_3);
        }
        float b0, b1;
        {
            const float s_0 = bit1 ? a0 : a2;
            const float s_1 = bit1 ? a1 : a3;
            const float k_0 = bit1 ? a2 : a0;
            const float k_1 = bit1 ? a3 : a1;
            b0 = k_0 + dppf<0x4E>(s_0);
            b1 = k_1 + dppf<0x4E>(s_1);
        }
        float S;
        {
            const float s_ = bit4 ? b0 : b1;
            const float k_ = bit4 ? b1 : b0;
            S = k_ + __shfl_xor(s_, 16, 64);
        }
        // broadcast-reduce lane bits 2, 3, 5
        S += __shfl_xor(S, 4, 64);
        S += dppf<0x108>(S) + dppf<0x118>(S);
        S += __shfl_xor(S, 32, 64);

        // allgather: E[m] = total for cluster v ^ m
        const float E0 = S;
        const float E1 = __shfl_xor(S, 16, 64);
        const float E2 = dppf<0x4E>(E0);
        const float E3 = dppf<0x4E>(E1);
        const float E4 = dppf<0xB1>(E0);
        const float E5 = dppf<0xB1>(E1);
        const float E6 = dppf<0xB1>(E2);
        const float E7 = dppf<0xB1>(E3);

        const float mn = fminf(fminf(fminf(E0,E1),fminf(E2,E3)),
                               fminf(fminf(E4,E5),fminf(E6,E7)));
        float W[KK];
        W[0]=__expf(mn-E0); W[1]=__expf(mn-E1); W[2]=__expf(mn-E2); W[3]=__expf(mn-E3);
        W[4]=__expf(mn-E4); W[5]=__expf(mn-E5); W[6]=__expf(mn-E6); W[7]=__expf(mn-E7);
        const float ssum = ((W[0]+W[1])+(W[2]+W[3])) + ((W[4]+W[5])+(W[6]+W[7]));
        const float inv  = 1.0f / ssum;

        const float xx0 = cx.x*cx.x, xx1 = cx.y*cx.y;
        const float xx2 = cx.z*cx.z, xx3 = cx.w*cx.w;
        #pragma unroll
        for (int m = 0; m < KK; ++m) {
            const float w = W[m] * inv;
            accw[m] += w;
            accx[m][0]  = fmaf(w, cx.x, accx[m][0]);
            accx[m][1]  = fmaf(w, cx.y, accx[m][1]);
            accx[m][2]  = fmaf(w, cx.z, accx[m][2]);
            accx[m][3]  = fmaf(w, cx.w, accx[m][3]);
            accx2[m][0] = fmaf(w, xx0, accx2[m][0]);
            accx2[m][1] = fmaf(w, xx1, accx2[m][1]);
            accx2[m][2] = fmaf(w, xx2, accx2[m][2]);
            accx2[m][3] = fmaf(w, xx3, accx2[m][3]);
        }
    }

    __syncthreads();

    // epilogue: unpermute k = v ^ m, combine across waves in LDS
    #pragma unroll
    for (int m = 0; m < KK; ++m) {
        const int k = v ^ m;
        float* p = &lds_acc[k * 512 + 4 * lane];
        atomicAdd(p + 0,   accx[m][0]);  atomicAdd(p + 1,   accx[m][1]);
        atomicAdd(p + 2,   accx[m][2]);  atomicAdd(p + 3,   accx[m][3]);
        atomicAdd(p + 256, accx2[m][0]); atomicAdd(p + 257, accx2[m][1]);
        atomicAdd(p + 258, accx2[m][2]); atomicAdd(p + 259, accx2[m][3]);
    }
    if (lane == 0) {   // lane 0 has v=0 -> accw[m] is cluster m's weight sum
        #pragma unroll
        for (int m = 0; m < KK; ++m) atomicAdd(&lds_w[m], accw[m]);
    }
    __syncthreads();

    float* dst = ws_wx + (size_t)(b * C + c) * (KK * 512);
    #pragma unroll
    for (int i = 0; i < (KK * 512) / 256; ++i)
        dst[i * 256 + tid] = lds_acc[i * 256 + tid];
    if (tid < KK) ws_w[(size_t)(b * C + c) * KK + tid] = lds_w[tid];
}

// ---------------------------------------------------------------------------
// Final: per (b,k). 1024 threads: 8 chunk-octets sum in parallel (8 waves/
// block instead of round-3's 4, and 8x fewer serial loads per thread), then
// mean/var (reference decomposition) + layernorm over 512, write out.
// ---------------------------------------------------------------------------
__global__ __launch_bounds__(1024) void lde_final4(
    const float* __restrict__ ws_wx,
    const float* __restrict__ ws_w,
    const float* __restrict__ centers,
    float* __restrict__ out,
    int C)
{
    const int b   = blockIdx.x >> 3;
    const int k   = blockIdx.x & 7;
    const int tid = threadIdx.x;
    const int oct = tid >> 7;        // 0..7
    const int j   = tid & 127;       // float4 index within the 512-chunk

    const float4* base = reinterpret_cast<const float4*>(ws_wx);
    float ax = 0.f, ay = 0.f, az = 0.f, aw = 0.f;
    for (int ci = oct; ci < C; ci += 8) {
        const float4 vv = base[((size_t)((b * C + ci) * KK + k)) * 128 + j];
        ax += vv.x; ay += vv.y; az += vv.z; aw += vv.w;
    }

    __shared__ float4 part[1024];
    __shared__ float  sum[512];
    __shared__ float  swbuf[64];
    part[tid] = make_float4(ax, ay, az, aw);
    if (tid >= 512 && tid < 512 + C)
        swbuf[tid - 512] = ws_w[(size_t)(b * C + (tid - 512)) * KK + k];
    __syncthreads();

    if (tid < 128) {
        float4 t = part[tid];
        #pragma unroll
        for (int o = 1; o < 8; ++o) {
            const float4 u = part[o * 128 + tid];
            t.x += u.x; t.y += u.y; t.z += u.z; t.w += u.w;
        }
        reinterpret_cast<float4*>(sum)[tid] = t;
    }
    __syncthreads();

    if (tid < 256) {
        float sw = 0.0f;
        for (int ci = 0; ci < C; ++ci) sw += swbuf[ci];   // LDS broadcast reads
        const int d = tid;
        const float wx   = sum[d];
        const float wx2  = sum[256 + d];
        const float ck   = centers[k * DD + d];
        const float mean = wx - ck * sw;
        const float E    = wx2 - 2.0f * ck * wx + ck * ck * sw;
        const float var  = E - mean * mean;
        sum[d]       = mean;    // in-place: same thread read both halves
        sum[256 + d] = var;
    }
    __syncthreads();

    // layernorm stats over sum[0..511]; all 16 waves participate (zeros above)
    float val = (tid < 512) ? sum[tid] : 0.0f;
    float s1 = val, s2 = val * val;
    #pragma unroll
    for (int off = 32; off >= 1; off >>= 1) {
        s1 += __shfl_xor(s1, off, 64);
        s2 += __shfl_xor(s2, off, 64);
    }
    __shared__ float l1[16], l2[16];
    const int wv = tid >> 6, lane = tid & 63;
    if (lane == 0) { l1[wv] = s1; l2[wv] = s2; }
    __syncthreads();
    float S1 = 0.f, S2 = 0.f;
    #pragma unroll
    for (int i = 0; i < 16; ++i) { S1 += l1[i]; S2 += l2[i]; }

    const float mu   = S1 * (1.0f / 512.0f);
    const float vr   = S2 * (1.0f / 512.0f) - mu * mu;
    const float rinv = rsqrtf(vr + LN_EPS);

    if (tid < 512) {
        const size_t o = (size_t)b * (KK * 512) + (size_t)k * 512;
        out[o + tid] = (val - mu) * rinv;
    }
}

// ---------------------------------------------------------------------------
extern "C" void kernel_launch(void* const* d_in, const int* in_sizes, int n_in,
                              void* d_out, int out_size, void* d_ws, size_t ws_size,
                              hipStream_t stream)
{
    const float* x       = (const float*)d_in[0];
    const float* centers = (const float*)d_in[1];
    const float* scale   = (const float*)d_in[2];
    const float* temp    = (const float*)d_in[3];
    float* out = (float*)d_out;

    int C = 64;  // ws >= 16.8MB confirmed round 3 (WRITE_SIZE); keep fallback
    while (C > 2 && ((size_t)BB * C * KK * 512 + (size_t)BB * C * KK) * 4 > ws_size)
        C >>= 1;
    const int TPW = TT / (C * 4);

    float* ws_wx = (float*)d_ws;
    float* ws_w  = ws_wx + (size_t)BB * C * KK * 512;

    dim3 g1(C, BB);
    lde_fused<<<g1, 256, 0, stream>>>(x, centers, scale, temp, ws_wx, ws_w, C, TPW);
    lde_final4<<<BB * KK, 1024, 0, stream>>>(ws_wx, ws_w, centers, out, C);
}

// Round 5
// 93.304 us; speedup vs baseline: 2.4673x; 1.9112x over previous
//
#include <hip/hip_runtime.h>
#include <math.h>

#define BB 16
#define TT 2048
#define DD 256
#define KK 8
#define TILE 16      // tokens per block-tile (phase1: 4/wave, phase2: all 16)
static constexpr float LN_EPS = 1e-5f;

// DPP lane exchange (VALU pipe). 0xB1=quad_perm xor1, 0x4E=quad_perm xor2,
// 0x108=row_shl:8, 0x118=row_shr:8 (16-lane rows, zero-fill).
template<int CTRL>
__device__ __forceinline__ float dppf(float x) {
    return __int_as_float(__builtin_amdgcn_update_dpp(
        0, __float_as_int(x), CTRL, 0xF, 0xF, true));
}

// ---------------------------------------------------------------------------
// Two-phase fused kernel. Register-pressure-proof: phase 1 computes softmax
// weights (no accumulators in flight beyond 18 regs), phase 2 accumulates
// 2 clusters per wave (x re-read from global, L1-hot). Peak live ~75 VGPRs.
// ---------------------------------------------------------------------------
__global__ __launch_bounds__(256, 4) void lde_fused2(
    const float* __restrict__ x,
    const float* __restrict__ centers,
    const float* __restrict__ scale,
    const float* __restrict__ temperature,
    float* __restrict__ ws_wx,   // [BB*C][KK*512] (0..255 wx | 256..511 wx2)
    float* __restrict__ ws_w,    // [BB*C][KK]
    int C, int NT)               // NT = tiles per block = (TT/C)/TILE
{
    const int c    = blockIdx.x;
    const int b    = blockIdx.y;
    const int tid  = threadIdx.x;
    const int wave = tid >> 6;       // 0..3
    const int lane = tid & 63;

    __shared__ float wbuf[TILE * KK];   // 512 B: tile weights, true k-order

    // Per-lane center fragments with -2*temp*scale folded in.
    // A[k] = temp*scale[k] is lane-uniform -> SGPR. Bc[k] per-lane partial.
    const float4* cv = reinterpret_cast<const float4*>(centers);
    const float temp = temperature[0];
    float4 c4s[KK]; float A[KK], Bc[KK];
    #pragma unroll
    for (int k = 0; k < KK; ++k) {
        const float4 cc = cv[k * 64 + lane];
        const float a = temp * scale[k];
        A[k]  = a;
        Bc[k] = a * (cc.x*cc.x + cc.y*cc.y + cc.z*cc.z + cc.w*cc.w);
        const float na = -2.0f * a;
        c4s[k] = make_float4(na*cc.x, na*cc.y, na*cc.z, na*cc.w);
    }

    const int bit0 = lane & 1;
    const int bit1 = (lane >> 1) & 1;
    const int bit4 = (lane >> 4) & 1;
    const int v    = (bit0 << 2) | (bit1 << 1) | bit4;  // lane's cluster after reduce
    const bool writer = ((lane & 44) == 0);  // lanes 0-3,16-19: v covers 0..7 once

    // Phase-2 accumulators: clusters kA=2*wave, kB=2*wave+1. 18 regs.
    float4 axA = {0,0,0,0}, ax2A = {0,0,0,0};
    float4 axB = {0,0,0,0}, ax2B = {0,0,0,0};
    float  aw0 = 0.0f, aw1 = 0.0f;

    const int TC = NT * TILE;                 // tokens per block
    const float4* xr = reinterpret_cast<const float4*>(x + (size_t)b * TT * DD);

    for (int tile = 0; tile < NT; ++tile) {
        const int tb = c * TC + tile * TILE;  // batch-local token base

        // ---------------- Phase 1: weights for this tile (wave-per-token)
        #pragma unroll
        for (int j = 0; j < TILE / 4; ++j) {
            const int tloc = wave * (TILE / 4) + j;
            const float4 cx = xr[(size_t)(tb + tloc) * 64 + lane];

            const float x2p = fmaf(cx.x,cx.x, fmaf(cx.y,cx.y,
                              fmaf(cx.z,cx.z, cx.w*cx.w)));
            float q[KK];
            #pragma unroll
            for (int k = 0; k < KK; ++k) {
                const float rp = fmaf(cx.x,c4s[k].x, fmaf(cx.y,c4s[k].y,
                                 fmaf(cx.z,c4s[k].z, cx.w*c4s[k].w)));
                q[k] = rp + fmaf(A[k], x2p, Bc[k]);
            }

            // halving reduce over lane bits 0 (qp xor1), 1 (qp xor2), 4 (shfl16)
            float a0, a1, a2, a3;
            {
                const float s_0 = bit0 ? q[0] : q[4];
                const float s_1 = bit0 ? q[1] : q[5];
                const float s_2 = bit0 ? q[2] : q[6];
                const float s_3 = bit0 ? q[3] : q[7];
                const float k_0 = bit0 ? q[4] : q[0];
                const float k_1 = bit0 ? q[5] : q[1];
                const float k_2 = bit0 ? q[6] : q[2];
                const float k_3 = bit0 ? q[7] : q[3];
                a0 = k_0 + dppf<0xB1>(s_0);
                a1 = k_1 + dppf<0xB1>(s_1);
                a2 = k_2 + dppf<0xB1>(s_2);
                a3 = k_3 + dppf<0xB1>(s_3);
            }
            float b0, b1;
            {
                const float s_0 = bit1 ? a0 : a2;
                const float s_1 = bit1 ? a1 : a3;
                const float k_0 = bit1 ? a2 : a0;
                const float k_1 = bit1 ? a3 : a1;
                b0 = k_0 + dppf<0x4E>(s_0);
                b1 = k_1 + dppf<0x4E>(s_1);
            }
            float S;
            {
                const float s_ = bit4 ? b0 : b1;
                const float k_ = bit4 ? b1 : b0;
                S = k_ + __shfl_xor(s_, 16, 64);
            }
            // broadcast-reduce lane bits 2, 3, 5 -> S = full total for cluster v
            S += __shfl_xor(S, 4, 64);
            S += dppf<0x108>(S) + dppf<0x118>(S);
            S += __shfl_xor(S, 32, 64);

            // own-cluster softmax weight: min/sum butterflies over v-groups
            float mn = S;
            mn = fminf(mn, dppf<0xB1>(mn));
            mn = fminf(mn, dppf<0x4E>(mn));
            mn = fminf(mn, __shfl_xor(mn, 16, 64));
            const float e = __expf(mn - S);
            float den = e;
            den += dppf<0xB1>(den);
            den += dppf<0x4E>(den);
            den += __shfl_xor(den, 16, 64);
            const float wn = e / den;

            if (writer) wbuf[tloc * KK + v] = wn;
        }
        __syncthreads();

        // ---------------- Phase 2: accumulate 2 clusters/wave over tile
        #pragma unroll 4
        for (int t = 0; t < TILE; ++t) {
            const float4 cx = xr[(size_t)(tb + t) * 64 + lane];   // L1-hot
            const float2 wk = *reinterpret_cast<const float2*>(
                                  &wbuf[t * KK + 2 * wave]);      // LDS broadcast
            aw0 += wk.x;  aw1 += wk.y;
            const float xx0 = cx.x*cx.x, xx1 = cx.y*cx.y;
            const float xx2 = cx.z*cx.z, xx3 = cx.w*cx.w;
            axA.x  = fmaf(wk.x, cx.x, axA.x);   axA.y  = fmaf(wk.x, cx.y, axA.y);
            axA.z  = fmaf(wk.x, cx.z, axA.z);   axA.w  = fmaf(wk.x, cx.w, axA.w);
            ax2A.x = fmaf(wk.x, xx0, ax2A.x);   ax2A.y = fmaf(wk.x, xx1, ax2A.y);
            ax2A.z = fmaf(wk.x, xx2, ax2A.z);   ax2A.w = fmaf(wk.x, xx3, ax2A.w);
            axB.x  = fmaf(wk.y, cx.x, axB.x);   axB.y  = fmaf(wk.y, cx.y, axB.y);
            axB.z  = fmaf(wk.y, cx.z, axB.z);   axB.w  = fmaf(wk.y, cx.w, axB.w);
            ax2B.x = fmaf(wk.y, xx0, ax2B.x);   ax2B.y = fmaf(wk.y, xx1, ax2B.y);
            ax2B.z = fmaf(wk.y, xx2, ax2B.z);   ax2B.w = fmaf(wk.y, xx3, ax2B.w);
        }
        __syncthreads();   // before next tile overwrites wbuf
    }

    // Epilogue: each wave exclusively owns clusters 2w,2w+1 -> direct stores.
    const size_t base = (size_t)(b * C + c) * (KK * 512);
    const int kA = 2 * wave, kB = 2 * wave + 1;
    *reinterpret_cast<float4*>(ws_wx + base + kA*512       + 4*lane) = axA;
    *reinterpret_cast<float4*>(ws_wx + base + kA*512 + 256 + 4*lane) = ax2A;
    *reinterpret_cast<float4*>(ws_wx + base + kB*512       + 4*lane) = axB;
    *reinterpret_cast<float4*>(ws_wx + base + kB*512 + 256 + 4*lane) = ax2B;
    if (lane == 0) {
        ws_w[(size_t)(b * C + c) * KK + kA] = aw0;
        ws_w[(size_t)(b * C + c) * KK + kB] = aw1;
    }
}

// ---------------------------------------------------------------------------
// Final: per (b,k). 1024 threads, 8 chunk-octets sum in parallel, then
// mean/var (reference decomposition) + layernorm over 512, write out.
// ---------------------------------------------------------------------------
__global__ __launch_bounds__(1024) void lde_final4(
    const float* __restrict__ ws_wx,
    const float* __restrict__ ws_w,
    const float* __restrict__ centers,
    float* __restrict__ out,
    int C)
{
    const int b   = blockIdx.x >> 3;
    const int k   = blockIdx.x & 7;
    const int tid = threadIdx.x;
    const int oct = tid >> 7;
    const int j   = tid & 127;

    const float4* base = reinterpret_cast<const float4*>(ws_wx);
    float ax = 0.f, ay = 0.f, az = 0.f, aw = 0.f;
    for (int ci = oct; ci < C; ci += 8) {
        const float4 vv = base[((size_t)((b * C + ci) * KK + k)) * 128 + j];
        ax += vv.x; ay += vv.y; az += vv.z; aw += vv.w;
    }

    __shared__ float4 part[1024];
    __shared__ float  sum[512];
    __shared__ float  swbuf[64];
    part[tid] = make_float4(ax, ay, az, aw);
    if (tid >= 512 && tid < 512 + C)
        swbuf[tid - 512] = ws_w[(size_t)(b * C + (tid - 512)) * KK + k];
    __syncthreads();

    if (tid < 128) {
        float4 t = part[tid];
        #pragma unroll
        for (int o = 1; o < 8; ++o) {
            const float4 u = part[o * 128 + tid];
            t.x += u.x; t.y += u.y; t.z += u.z; t.w += u.w;
        }
        reinterpret_cast<float4*>(sum)[tid] = t;
    }
    __syncthreads();

    if (tid < 256) {
        float sw = 0.0f;
        for (int ci = 0; ci < C; ++ci) sw += swbuf[ci];
        const int d = tid;
        const float wx   = sum[d];
        const float wx2  = sum[256 + d];
        const float ck   = centers[k * DD + d];
        const float mean = wx - ck * sw;
        const float E    = wx2 - 2.0f * ck * wx + ck * ck * sw;
        const float var  = E - mean * mean;
        sum[d]       = mean;
        sum[256 + d] = var;
    }
    __syncthreads();

    float val = (tid < 512) ? sum[tid] : 0.0f;
    float s1 = val, s2 = val * val;
    #pragma unroll
    for (int off = 32; off >= 1; off >>= 1) {
        s1 += __shfl_xor(s1, off, 64);
        s2 += __shfl_xor(s2, off, 64);
    }
    __shared__ float l1[16], l2[16];
    const int wv = tid >> 6, lane = tid & 63;
    if (lane == 0) { l1[wv] = s1; l2[wv] = s2; }
    __syncthreads();
    float S1 = 0.f, S2 = 0.f;
    #pragma unroll
    for (int i = 0; i < 16; ++i) { S1 += l1[i]; S2 += l2[i]; }

    const float mu   = S1 * (1.0f / 512.0f);
    const float vr   = S2 * (1.0f / 512.0f) - mu * mu;
    const float rinv = rsqrtf(vr + LN_EPS);

    if (tid < 512) {
        const size_t o = (size_t)b * (KK * 512) + (size_t)k * 512;
        out[o + tid] = (val - mu) * rinv;
    }
}

// ---------------------------------------------------------------------------
extern "C" void kernel_launch(void* const* d_in, const int* in_sizes, int n_in,
                              void* d_out, int out_size, void* d_ws, size_t ws_size,
                              hipStream_t stream)
{
    const float* x       = (const float*)d_in[0];
    const float* centers = (const float*)d_in[1];
    const float* scale   = (const float*)d_in[2];
    const float* temp    = (const float*)d_in[3];
    float* out = (float*)d_out;

    int C = 64;   // ws >= 16.8 MB confirmed in rounds 3-4
    while (C > 2 && ((size_t)BB * C * KK * 512 + (size_t)BB * C * KK) * 4 > ws_size)
        C >>= 1;
    const int NT = (TT / C) / TILE;

    float* ws_wx = (float*)d_ws;
    float* ws_w  = ws_wx + (size_t)BB * C * KK * 512;

    dim3 g1(C, BB);
    lde_fused2<<<g1, 256, 0, stream>>>(x, centers, scale, temp, ws_wx, ws_w, C, NT);
    lde_final4<<<BB * KK, 1024, 0, stream>>>(ws_wx, ws_w, centers, out, C);
}